// Round 17
// baseline (192.936 us; speedup 1.0000x reference)
//
#include <hip/hip_runtime.h>
#include <stdint.h>

#define SEQ    2048
#define DMODEL 1024
#define NHEADS 16
#define HDIM   64
#define BATCH  4
#define MTOT   (BATCH*SEQ)

typedef __attribute__((ext_vector_type(8)))  short s16x8;
typedef __attribute__((ext_vector_type(4)))  short s16x4;
typedef __attribute__((ext_vector_type(4)))  float f32x4;
typedef __attribute__((ext_vector_type(16))) float f32x16;

// ---- workspace offsets (bytes) ----
#define OFF_SIN  ((size_t)0)          // 2048*32*4
#define OFF_COS  ((size_t)262144)
#define OFF_XHI  ((size_t)524288)     // 8192*1024*2
#define OFF_WQH  ((size_t)34078720)
#define OFF_WKH  ((size_t)38273024)
#define OFF_WVH  ((size_t)42467328)
#define OFF_WOH  ((size_t)46661632)
#define OFF_QR   ((size_t)50855936)   // [b,h,n,dh] bf16 (Q pre-scaled by 0.125*log2e)
#define OFF_KR   ((size_t)67633152)
#define OFF_VT   ((size_t)84410368)   // [b,h,dh,n] bf16 (transposed)
#define OFF_AHI  ((size_t)101187584)  // attn out [m,e] bf16

#define QSCALE 0.18033688011112042f

__device__ __forceinline__ uint16_t f2bf(float f){
  union{float f;uint32_t u;}v; v.f=f;
  uint32_t r=v.u+0x7fffu+((v.u>>16)&1u);
  return (uint16_t)(r>>16);
}
__device__ __forceinline__ float bf2f(uint16_t u){
  union{uint32_t u;float f;}v; v.u=((uint32_t)u)<<16; return v.f;
}

__device__ __forceinline__ void async16(void* lds, const void* g){
  __builtin_amdgcn_global_load_lds(
    (const __attribute__((address_space(1))) void*)g,
    (__attribute__((address_space(3))) void*)lds, 16, 0, 0);
}

__device__ __forceinline__ float fexp2(float x){
#if __has_builtin(__builtin_amdgcn_exp2f)
  return __builtin_amdgcn_exp2f(x);
#else
  float r; asm("v_exp_f32 %0, %1" : "=v"(r) : "v"(x)); return r;
#endif
}
__device__ __forceinline__ float frcp(float x){
#if __has_builtin(__builtin_amdgcn_rcpf)
  return __builtin_amdgcn_rcpf(x);
#else
  float r; asm("v_rcp_f32 %0, %1" : "=v"(r) : "v"(x)); return r;
#endif
}
// {o0,o1} = permlane32_swap(a,b)
__device__ __forceinline__ void plswap(unsigned a, unsigned b, unsigned &o0, unsigned &o1){
#if __has_builtin(__builtin_amdgcn_permlane32_swap)
  auto r = __builtin_amdgcn_permlane32_swap(a, b, false, false);
  o0 = (unsigned)r[0]; o1 = (unsigned)r[1];
#else
  unsigned ax = (unsigned)__shfl_xor((int)a, 32, 64);
  unsigned bx = (unsigned)__shfl_xor((int)b, 32, 64);
  bool hi = (threadIdx.x & 32) != 0;
  o0 = hi ? bx : a;
  o1 = hi ? b  : ax;
#endif
}

// ---------------- fused prep: bf16 converts (x, 4 W) + RoPE tables, one launch ----------------
__global__ __launch_bounds__(256) void prep_k(
  const float* __restrict__ x,
  const float* __restrict__ Wq, const float* __restrict__ Wk,
  const float* __restrict__ Wv, const float* __restrict__ Wo,
  uint16_t* __restrict__ xhi, uint16_t* __restrict__ wqh, uint16_t* __restrict__ wkh,
  uint16_t* __restrict__ wvh, uint16_t* __restrict__ woh,
  float* __restrict__ st, float* __restrict__ ct)
{
  int b = blockIdx.x;
  if (b < 12288){
    const float* s; uint16_t* d; int i;
    if (b < 8192){ s = x; d = xhi; i = b*256 + threadIdx.x; }
    else {
      int wsel = (b - 8192) >> 10;
      int lb   = (b - 8192) & 1023;
      s = wsel==0? Wq : wsel==1? Wk : wsel==2? Wv : Wo;
      d = wsel==0? wqh: wsel==1? wkh: wsel==2? wvh: woh;
      i = lb*256 + threadIdx.x;
    }
    f32x4 v = *(const f32x4*)(s + (size_t)i*4);
    s16x4 vh;
    #pragma unroll
    for(int r=0;r<4;r++) vh[r] = (short)f2bf(v[r]);
    *(s16x4*)(d + (size_t)i*4) = vh;
  } else {
    int i = (b - 12288)*256 + threadIdx.x;   // < 65536
    int n = i>>5, j = i&31;
    float freq = powf(10000.f, -(float)j/32.f);
    float ang = (float)n*freq;
    st[i] = sinf(ang);
    ct[i] = cosf(ang);
  }
}

// ---------------- GEMM core (128x128 tile, BK=64, XOR-swizzled LDS, kh-stagger) ----------------
__device__ __forceinline__ void gemm_mainloop64(
  const uint16_t* __restrict__ A, const uint16_t* __restrict__ B,
  int m0, int e0, char* lA, char* lB, f32x4 acc[4][4])
{
  const int t = threadIdx.x;
  const int lane = t & 63;
  const int wr = t>>7, wc = (t>>6)&1;
  const int lq = lane&15, lg = lane>>4;
  const int rowA = wr*64 + lq;
  const int rowB = wc*64 + lq;

  int dbyte[4], srow[4], sbyte[4];
  #pragma unroll
  for (int s=0;s<4;s++){
    int d = s*4096 + t*16;
    int r = d>>7, c = (d>>4)&7;
    dbyte[s]=d; srow[s]=r; sbyte[s]=(c ^ (r&7))*16;
  }
  int chh[2];
  #pragma unroll
  for (int kh=0;kh<2;kh++) chh[kh] = (((kh<<2)|lg) ^ (lq&7))*16;
  const bool oddw = ((t>>6) & 1) != 0;
  const int cF = oddw ? chh[1] : chh[0];
  const int cS = oddw ? chh[0] : chh[1];

  const char* Ab = (const char*)A;
  const char* Bb = (const char*)B;

  for (int k0=0; k0<DMODEL; k0+=64){
    #pragma unroll
    for (int s=0;s<4;s++){
      async16(lA + dbyte[s], Ab + (size_t)(m0+srow[s])*2048 + k0*2 + sbyte[s]);
      async16(lB + dbyte[s], Bb + (size_t)(e0+srow[s])*2048 + k0*2 + sbyte[s]);
    }
    __syncthreads();
    #pragma unroll
    for (int ph=0; ph<2; ++ph){
      const int ch = ph ? cS : cF;
      s16x8 af[4], bfr[4];
      #pragma unroll
      for (int mi=0;mi<4;mi++) af[mi]  = *(const s16x8*)(lA + (rowA+mi*16)*128 + ch);
      #pragma unroll
      for (int ni=0;ni<4;ni++) bfr[ni] = *(const s16x8*)(lB + (rowB+ni*16)*128 + ch);
      __builtin_amdgcn_s_setprio(1);
      #pragma unroll
      for (int mi=0;mi<4;mi++){
        #pragma unroll
        for (int ni=0;ni<4;ni++)
          acc[mi][ni] = __builtin_amdgcn_mfma_f32_16x16x32_bf16(af[mi], bfr[ni], acc[mi][ni],0,0,0);
      }
      __builtin_amdgcn_s_setprio(0);
    }
    __syncthreads();
  }
}

// ---------------- QKV projection + RoPE epilogue ----------------
__global__ __launch_bounds__(256) void gemm_qkv_k(
  const uint16_t* __restrict__ Xh,
  const uint16_t* __restrict__ WqH, const uint16_t* __restrict__ WkH, const uint16_t* __restrict__ WvH,
  const float* __restrict__ st, const float* __restrict__ ct,
  uint16_t* __restrict__ Qr, uint16_t* __restrict__ Kr, uint16_t* __restrict__ Vt)
{
  __shared__ char lA[128*128], lB[128*128];   // 16KB each
  // XCD-locality swizzle: each XCD owns 8 contiguous m-tiles (2MB A-panel, L2-fit).
  int mx = blockIdx.x;
  int m0 = (((mx & 7) << 3) | (mx >> 3)) * 128;
  int cti = blockIdx.y;
  int seg = cti>>3;                 // 0=Q 1=K 2=V
  int e0 = (cti&7)*128;
  const uint16_t* W = seg==0? WqH : (seg==1? WkH : WvH);
  f32x4 acc[4][4];
  #pragma unroll
  for(int i=0;i<4;i++){
    #pragma unroll
    for(int j=0;j<4;j++) acc[i][j] = (f32x4){0.f,0.f,0.f,0.f};
  }
  gemm_mainloop64(Xh, W, m0, e0, lA, lB, acc);

  int t=threadIdx.x, lane=t&63, lq=lane&15, lg=lane>>4;
  int wr=t>>7, wc=(t>>6)&1;
  int eb = e0 + wc*64;
  int h = eb>>6;
  int rbase = m0 + wr*64 + lg*4;
  if (seg<2){
    uint16_t* O = seg==0? Qr:Kr;
    float qs = seg==0 ? QSCALE : 1.0f;
    #pragma unroll
    for(int mi=0;mi<4;mi++){
      #pragma unroll
      for(int ni=0;ni<2;ni++){
        int j = ni*16+lq;
        #pragma unroll
        for(int r=0;r<4;r++){
          int m = rbase + mi*16 + r;
          int b = m>>11, n = m&2047;
          float sv = st[n*32+j], cv = ct[n*32+j];
          float x1 = acc[mi][ni][r], x2 = acc[mi][ni+2][r];
          size_t base = ((size_t)((b*NHEADS+h)*SEQ + n))*HDIM;
          O[base + j]      = f2bf((x1*cv - x2*sv)*qs);
          O[base + j + 32] = f2bf((x1*sv + x2*cv)*qs);
        }
      }
    }
  } else {
    #pragma unroll
    for(int mi=0;mi<4;mi++){
      #pragma unroll
      for(int ni=0;ni<4;ni++){
        int dh = ni*16+lq;
        int m = rbase + mi*16;
        int b = m>>11, n = m&2047;
        s16x4 v;
        #pragma unroll
        for(int r=0;r<4;r++) v[r] = (short)f2bf(acc[mi][ni][r]);
        *(s16x4*)(Vt + ((size_t)((b*NHEADS+h)*HDIM + dh))*SEQ + n) = v;
      }
    }
  }
}

// ---------------- flash attention: 16-wave blocks (1024 thr, 512 q), 1 async16/thread/tile ----------------
// Waves 0-7 stage K, waves 8-15 stage V (wave-uniform split); per-thread source pointer
// fully strength-reduced (1 add/tile). Residency: 1 block/CU x 16 waves = 16 waves/CU (unchanged).
__global__ __launch_bounds__(1024, 4) void attn_k(
  const uint16_t* __restrict__ Qr, const uint16_t* __restrict__ Kr, const uint16_t* __restrict__ Vt,
  uint16_t* __restrict__ Ah)
{
  __shared__ char lds[32768];

  int bid = blockIdx.x;
  int w = (bid & 7)*32 + (bid >> 3);    // XCD swizzle: 8 bh per XCD (4MB K/V = one XCD L2)
  int bh = w >> 2, qt = w & 3;
  int tid = threadIdx.x;
  int wid = tid >> 6, lane = tid & 63;
  int l31 = lane & 31, hi = lane >> 5;
  int q0 = qt*512 + wid*32;

  const uint16_t* Qb = Qr + (size_t)bh*SEQ*HDIM;
  const uint16_t* Kb = Kr + (size_t)bh*SEQ*HDIM;
  const uint16_t* Vb = Vt + (size_t)bh*HDIM*SEQ;

  s16x8 qf[4];
  #pragma unroll
  for (int sp=0; sp<4; ++sp)
    qf[sp] = *(const s16x8*)(Qb + (size_t)(q0 + l31)*HDIM + sp*16 + hi*8);

  s16x8 ones;
  #pragma unroll
  for (int j=0;j<8;j++) ones[j] = (short)0x3F80;

  f32x16 zm16;
  #pragma unroll
  for (int r=0;r<16;r++) zm16[r] = -16.0f;

  f32x16 oa[2], lacc;
  #pragma unroll
  for (int r=0;r<16;r++){ oa[0][r]=0.f; oa[1][r]=0.f; lacc[r]=0.f; }

  const int e7 = l31 & 7;
  const int rK = l31*128;
  const int kOff[4]  = { (((0+hi)^e7)<<4), (((2+hi)^e7)<<4), (((4+hi)^e7)<<4), (((6+hi)^e7)<<4) };
  const int vA0 = (((0+hi)^e7)<<4), vA1 = (((2+hi)^e7)<<4);   // sub0
  const int vB0 = (((4+hi)^e7)<<4), vB1 = (((6+hi)^e7)<<4);   // sub1
  const bool odd = (wid & 1) != 0;
  const int kBaseF = odd ? 4096 : 0,   kBaseS = odd ? 0 : 4096;
  const int vF0 = odd ? vB0 : vA0,     vF1 = odd ? vB1 : vA1;
  const int vS0 = odd ? vA0 : vB0,     vS1 = odd ? vA1 : vB1;

  // one async16 per thread per tile; K for waves 0-7, V for waves 8-15 (wave-uniform)
  const bool isK = (tid < 512);
  const int ci = isK ? tid : (tid - 512);
  const int sck = ci ^ ((ci>>3)&7);
  const int rowv = ci>>3;
  const int scv = (ci&7) ^ (rowv&7);
  const char* src = isK ? ((const char*)Kb + sck*16)
                        : ((const char*)Vb + (size_t)rowv*4096 + scv*16);
  const ptrdiff_t sstep = isK ? 8192 : 128;
  char* const dst0 = lds + (isK ? ci*16 : 16384 + ci*16);

  // prologue: stage tile 0 into buf0
  async16(dst0, src); src += sstep;
  asm volatile("s_waitcnt vmcnt(0)" ::: "memory");
  __syncthreads();

  auto SUBSTEP = [&](const char* bK, const char* bV, int kbase, int v0, int v1){
    s16x8 kf[4];
    #pragma unroll
    for (int sp=0; sp<4; ++sp)
      kf[sp] = *(const s16x8*)(bK + kbase + rK + kOff[sp]);
    f32x16 sacc = zm16;
    __builtin_amdgcn_s_setprio(1);
    #pragma unroll
    for (int sp=0; sp<4; ++sp)
      sacc = __builtin_amdgcn_mfma_f32_32x32x16_bf16(kf[sp], qf[sp], sacc, 0,0,0);
    __builtin_amdgcn_s_setprio(0);
    s16x8 vf[4];
    #pragma unroll
    for (int db=0; db<2; ++db){
      vf[db*2+0] = *(const s16x8*)(bV + db*4096 + rK + v0);
      vf[db*2+1] = *(const s16x8*)(bV + db*4096 + rK + v1);
    }
    float p[16];
    #pragma unroll
    for (int r=0;r<16;r++) p[r] = fexp2(sacc[r]);
    uint32_t pw[8];
    #pragma unroll
    for (int j=0;j<8;j++)
      asm("v_cvt_pk_bf16_f32 %0, %1, %2" : "=v"(pw[j]) : "v"(p[2*j]), "v"(p[2*j+1]));
    unsigned w0,w1,w2,w3, x0,x1,x2,x3;
    plswap(pw[0], pw[2], w0, w2);
    plswap(pw[1], pw[3], w1, w3);
    plswap(pw[4], pw[6], x0, x2);
    plswap(pw[5], pw[7], x1, x3);
    union { uint32_t wd[4]; s16x8 v; } pa0, pa1;
    pa0.wd[0]=w0; pa0.wd[1]=w1; pa0.wd[2]=w2; pa0.wd[3]=w3;
    pa1.wd[0]=x0; pa1.wd[1]=x1; pa1.wd[2]=x2; pa1.wd[3]=x3;
    __builtin_amdgcn_s_setprio(1);
    oa[0] = __builtin_amdgcn_mfma_f32_32x32x16_bf16(pa0.v, vf[0], oa[0], 0,0,0);
    oa[0] = __builtin_amdgcn_mfma_f32_32x32x16_bf16(pa1.v, vf[1], oa[0], 0,0,0);
    oa[1] = __builtin_amdgcn_mfma_f32_32x32x16_bf16(pa0.v, vf[2], oa[1], 0,0,0);
    oa[1] = __builtin_amdgcn_mfma_f32_32x32x16_bf16(pa1.v, vf[3], oa[1], 0,0,0);
    lacc = __builtin_amdgcn_mfma_f32_32x32x16_bf16(pa0.v, ones, lacc, 0,0,0);
    lacc = __builtin_amdgcn_mfma_f32_32x32x16_bf16(pa1.v, ones, lacc, 0,0,0);
    __builtin_amdgcn_s_setprio(0);
  };

  const int NT = SEQ/64;
  for (int t=0; t<NT; ++t){
    int cur = t & 1;
    if (t+1 < NT){                       // stage tile t+1 into buf cur^1
      async16(dst0 + (cur^1)*8192, src);
      src += sstep;
    }
    const char* bK = lds + cur*8192;
    const char* bV = lds + 16384 + cur*8192;
    SUBSTEP(bK, bV, kBaseF, vF0, vF1);
    SUBSTEP(bK, bV, kBaseS, vS0, vS1);
    asm volatile("s_waitcnt vmcnt(0)" ::: "memory");
    __syncthreads();
  }

  // epilogue: L already in acc layout; normalize and write bf16
  int b = bh >> 4, h = bh & 15;
  #pragma unroll
  for (int r=0;r<16;r++){
    int q = (r&3) + 8*(r>>2) + 4*hi;
    float inv = frcp(lacc[r]);
    size_t mrow = ((size_t)(b*SEQ + q0 + q))*DMODEL + (size_t)h*HDIM + l31;
    #pragma unroll
    for (int db=0; db<2; ++db)
      Ah[mrow + db*32] = f2bf(oa[db][r]*inv);
  }
}

// ---------------- output projection ----------------
__global__ __launch_bounds__(256) void gemm_out_k(
  const uint16_t* __restrict__ Ahp, const uint16_t* __restrict__ WoH, float* __restrict__ C)
{
  __shared__ char lA[128*128], lB[128*128];
  int mx = blockIdx.x;
  int m0 = (((mx & 7) << 3) | (mx >> 3)) * 128;   // XCD-locality swizzle
  int e0 = blockIdx.y*128;
  f32x4 acc[4][4];
  #pragma unroll
  for(int i=0;i<4;i++){
    #pragma unroll
    for(int j=0;j<4;j++) acc[i][j] = (f32x4){0.f,0.f,0.f,0.f};
  }
  gemm_mainloop64(Ahp, WoH, m0, e0, lA, lB, acc);
  int t=threadIdx.x, lane=t&63, lq=lane&15, lg=lane>>4;
  int wr=t>>7, wc=(t>>6)&1;
  int rbase = m0 + wr*64 + lg*4;
  int cb = e0 + wc*64;
  #pragma unroll
  for(int mi=0;mi<4;mi++){
    #pragma unroll
    for(int ni=0;ni<4;ni++){
      #pragma unroll
      for(int r=0;r<4;r++)
        C[(size_t)(rbase+mi*16+r)*DMODEL + cb + ni*16 + lq] = acc[mi][ni][r];
    }
  }
}

extern "C" void kernel_launch(void* const* d_in, const int* in_sizes, int n_in,
                              void* d_out, int out_size, void* d_ws, size_t ws_size,
                              hipStream_t stream) {
  const float* x  = (const float*)d_in[0];
  const float* Wq = (const float*)d_in[1];
  const float* Wk = (const float*)d_in[2];
  const float* Wv = (const float*)d_in[3];
  const float* Wo = (const float*)d_in[4];
  float* out = (float*)d_out;
  char* ws = (char*)d_ws;

  float* sin_t = (float*)(ws + OFF_SIN);
  float* cos_t = (float*)(ws + OFF_COS);
  uint16_t* xhi = (uint16_t*)(ws + OFF_XHI);
  uint16_t* wqh = (uint16_t*)(ws + OFF_WQH);
  uint16_t* wkh = (uint16_t*)(ws + OFF_WKH);
  uint16_t* wvh = (uint16_t*)(ws + OFF_WVH);
  uint16_t* woh = (uint16_t*)(ws + OFF_WOH);
  uint16_t* Qr  = (uint16_t*)(ws + OFF_QR);
  uint16_t* Kr  = (uint16_t*)(ws + OFF_KR);
  uint16_t* Vt  = (uint16_t*)(ws + OFF_VT);
  uint16_t* ahi = (uint16_t*)(ws + OFF_AHI);

  prep_k<<<dim3(12544),dim3(256),0,stream>>>(x, Wq, Wk, Wv, Wo,
                                             xhi, wqh, wkh, wvh, woh, sin_t, cos_t);

  gemm_qkv_k<<<dim3(MTOT/128, 24),dim3(256),0,stream>>>(xhi, wqh, wkh, wvh,
                                                        sin_t, cos_t, Qr, Kr, Vt);
  attn_k<<<dim3(BATCH*NHEADS*(SEQ/512)),dim3(1024),0,stream>>>(Qr, Kr, Vt, ahi);
  gemm_out_k<<<dim3(MTOT/128, 8),dim3(256),0,stream>>>(ahi, woh, out);
}

// Round 18
// 179.173 us; speedup vs baseline: 1.0768x; 1.0768x over previous
//
#include <hip/hip_runtime.h>
#include <stdint.h>

#define SEQ    2048
#define DMODEL 1024
#define NHEADS 16
#define HDIM   64
#define BATCH  4
#define MTOT   (BATCH*SEQ)

typedef __attribute__((ext_vector_type(8)))  short s16x8;
typedef __attribute__((ext_vector_type(4)))  short s16x4;
typedef __attribute__((ext_vector_type(4)))  float f32x4;
typedef __attribute__((ext_vector_type(16))) float f32x16;

// ---- workspace offsets (bytes) ----
#define OFF_SIN  ((size_t)0)          // 2048*32*4
#define OFF_COS  ((size_t)262144)
#define OFF_XHI  ((size_t)524288)     // 8192*1024*2
#define OFF_WQH  ((size_t)34078720)
#define OFF_WKH  ((size_t)38273024)
#define OFF_WVH  ((size_t)42467328)
#define OFF_WOH  ((size_t)46661632)
#define OFF_QR   ((size_t)50855936)   // [b,h,n,dh] bf16 (Q pre-scaled by 0.125*log2e)
#define OFF_KR   ((size_t)67633152)
#define OFF_VT   ((size_t)84410368)   // [b,h,dh,n] bf16 (transposed)
#define OFF_AHI  ((size_t)101187584)  // attn out [m,e] bf16

#define QSCALE 0.18033688011112042f

__device__ __forceinline__ uint16_t f2bf(float f){
  union{float f;uint32_t u;}v; v.f=f;
  uint32_t r=v.u+0x7fffu+((v.u>>16)&1u);
  return (uint16_t)(r>>16);
}
__device__ __forceinline__ float bf2f(uint16_t u){
  union{uint32_t u;float f;}v; v.u=((uint32_t)u)<<16; return v.f;
}

__device__ __forceinline__ void async16(void* lds, const void* g){
  __builtin_amdgcn_global_load_lds(
    (const __attribute__((address_space(1))) void*)g,
    (__attribute__((address_space(3))) void*)lds, 16, 0, 0);
}

__device__ __forceinline__ float fexp2(float x){
#if __has_builtin(__builtin_amdgcn_exp2f)
  return __builtin_amdgcn_exp2f(x);
#else
  float r; asm("v_exp_f32 %0, %1" : "=v"(r) : "v"(x)); return r;
#endif
}
__device__ __forceinline__ float frcp(float x){
#if __has_builtin(__builtin_amdgcn_rcpf)
  return __builtin_amdgcn_rcpf(x);
#else
  float r; asm("v_rcp_f32 %0, %1" : "=v"(r) : "v"(x)); return r;
#endif
}
// {o0,o1} = permlane32_swap(a,b)
__device__ __forceinline__ void plswap(unsigned a, unsigned b, unsigned &o0, unsigned &o1){
#if __has_builtin(__builtin_amdgcn_permlane32_swap)
  auto r = __builtin_amdgcn_permlane32_swap(a, b, false, false);
  o0 = (unsigned)r[0]; o1 = (unsigned)r[1];
#else
  unsigned ax = (unsigned)__shfl_xor((int)a, 32, 64);
  unsigned bx = (unsigned)__shfl_xor((int)b, 32, 64);
  bool hi = (threadIdx.x & 32) != 0;
  o0 = hi ? bx : a;
  o1 = hi ? b  : ax;
#endif
}

// ---------------- fused prep: bf16 converts (x, 4 W) + RoPE tables, one launch ----------------
__global__ __launch_bounds__(256) void prep_k(
  const float* __restrict__ x,
  const float* __restrict__ Wq, const float* __restrict__ Wk,
  const float* __restrict__ Wv, const float* __restrict__ Wo,
  uint16_t* __restrict__ xhi, uint16_t* __restrict__ wqh, uint16_t* __restrict__ wkh,
  uint16_t* __restrict__ wvh, uint16_t* __restrict__ woh,
  float* __restrict__ st, float* __restrict__ ct)
{
  int b = blockIdx.x;
  if (b < 12288){
    const float* s; uint16_t* d; int i;
    if (b < 8192){ s = x; d = xhi; i = b*256 + threadIdx.x; }
    else {
      int wsel = (b - 8192) >> 10;
      int lb   = (b - 8192) & 1023;
      s = wsel==0? Wq : wsel==1? Wk : wsel==2? Wv : Wo;
      d = wsel==0? wqh: wsel==1? wkh: wsel==2? wvh: woh;
      i = lb*256 + threadIdx.x;
    }
    f32x4 v = *(const f32x4*)(s + (size_t)i*4);
    s16x4 vh;
    #pragma unroll
    for(int r=0;r<4;r++) vh[r] = (short)f2bf(v[r]);
    *(s16x4*)(d + (size_t)i*4) = vh;
  } else {
    int i = (b - 12288)*256 + threadIdx.x;   // < 65536
    int n = i>>5, j = i&31;
    float freq = powf(10000.f, -(float)j/32.f);
    float ang = (float)n*freq;
    st[i] = sinf(ang);
    ct[i] = cosf(ang);
  }
}

// ---------------- GEMM core: 256x128 tile, BK=64, 512 thr / 8 waves, XOR-swizzled LDS ----------------
// Per-wave output 64x64 (acc[4][4], 16 MFMA : 8 ds_read per kh, unchanged ratio).
// Barriers per unit output halved vs the 128x128/256-thr version; B traffic halved.
__device__ __forceinline__ void gemm_mainloop64w(
  const uint16_t* __restrict__ A, const uint16_t* __restrict__ B,
  int m0, int e0, char* lA, char* lB, f32x4 acc[4][4])
{
  const int t = threadIdx.x;
  const int lane = t & 63;
  const int wid = t >> 6;           // 0..7
  const int wr = wid >> 1;          // 0..3 (m)
  const int wc = wid & 1;           // 0..1 (n)
  const int lq = lane&15, lg = lane>>4;
  const int rowA = wr*64 + lq;
  const int rowB = wc*64 + lq;

  // staging maps: A = 32KB (4 chunks/thread), B = 16KB (2 chunks/thread)
  int dA[4], rA[4], bA[4];
  #pragma unroll
  for (int s=0;s<4;s++){
    int ci = s*512 + t;             // 0..2047
    int row = ci>>3, c = ci&7;
    dA[s]=ci*16; rA[s]=row; bA[s]=(c ^ (row&7))*16;
  }
  int dB[2], rB[2], bB[2];
  #pragma unroll
  for (int s=0;s<2;s++){
    int ci = s*512 + t;             // 0..1023
    int row = ci>>3, c = ci&7;
    dB[s]=ci*16; rB[s]=row; bB[s]=(c ^ (row&7))*16;
  }
  int chh[2];
  #pragma unroll
  for (int kh=0;kh<2;kh++) chh[kh] = (((kh<<2)|lg) ^ (lq&7))*16;
  const bool oddw = (wid & 1) != 0;       // kh-stagger by wave parity
  const int cF = oddw ? chh[1] : chh[0];
  const int cS = oddw ? chh[0] : chh[1];

  const char* Ab = (const char*)A;
  const char* Bb = (const char*)B;

  for (int k0=0; k0<DMODEL; k0+=64){
    #pragma unroll
    for (int s=0;s<4;s++)
      async16(lA + dA[s], Ab + (size_t)(m0+rA[s])*2048 + k0*2 + bA[s]);
    #pragma unroll
    for (int s=0;s<2;s++)
      async16(lB + dB[s], Bb + (size_t)(e0+rB[s])*2048 + k0*2 + bB[s]);
    __syncthreads();
    #pragma unroll
    for (int ph=0; ph<2; ++ph){
      const int ch = ph ? cS : cF;
      s16x8 af[4], bfr[4];
      #pragma unroll
      for (int mi=0;mi<4;mi++) af[mi]  = *(const s16x8*)(lA + (rowA+mi*16)*128 + ch);
      #pragma unroll
      for (int ni=0;ni<4;ni++) bfr[ni] = *(const s16x8*)(lB + (rowB+ni*16)*128 + ch);
      __builtin_amdgcn_s_setprio(1);
      #pragma unroll
      for (int mi=0;mi<4;mi++){
        #pragma unroll
        for (int ni=0;ni<4;ni++)
          acc[mi][ni] = __builtin_amdgcn_mfma_f32_16x16x32_bf16(af[mi], bfr[ni], acc[mi][ni],0,0,0);
      }
      __builtin_amdgcn_s_setprio(0);
    }
    __syncthreads();
  }
}

// ---------------- QKV projection + RoPE epilogue ----------------
__global__ __launch_bounds__(512) void gemm_qkv_k(
  const uint16_t* __restrict__ Xh,
  const uint16_t* __restrict__ WqH, const uint16_t* __restrict__ WkH, const uint16_t* __restrict__ WvH,
  const float* __restrict__ st, const float* __restrict__ ct,
  uint16_t* __restrict__ Qr, uint16_t* __restrict__ Kr, uint16_t* __restrict__ Vt)
{
  __shared__ char lA[256*128], lB[128*128];   // 32KB + 16KB
  // XCD-locality swizzle: bijective on [0,32): each XCD owns 4 contiguous m-tiles.
  int mx = blockIdx.x;
  int m0 = (((mx & 7) << 2) | (mx >> 3)) * 256;
  int cti = blockIdx.y;
  int seg = cti>>3;                 // 0=Q 1=K 2=V
  int e0 = (cti&7)*128;
  const uint16_t* W = seg==0? WqH : (seg==1? WkH : WvH);
  f32x4 acc[4][4];
  #pragma unroll
  for(int i=0;i<4;i++){
    #pragma unroll
    for(int j=0;j<4;j++) acc[i][j] = (f32x4){0.f,0.f,0.f,0.f};
  }
  gemm_mainloop64w(Xh, W, m0, e0, lA, lB, acc);

  int t=threadIdx.x, lane=t&63, lq=lane&15, lg=lane>>4;
  int wid=t>>6, wr=wid>>1, wc=wid&1;
  int eb = e0 + wc*64;
  int h = eb>>6;
  int rbase = m0 + wr*64 + lg*4;
  if (seg<2){
    uint16_t* O = seg==0? Qr:Kr;
    float qs = seg==0 ? QSCALE : 1.0f;
    #pragma unroll
    for(int mi=0;mi<4;mi++){
      #pragma unroll
      for(int ni=0;ni<2;ni++){
        int j = ni*16+lq;
        #pragma unroll
        for(int r=0;r<4;r++){
          int m = rbase + mi*16 + r;
          int b = m>>11, n = m&2047;
          float sv = st[n*32+j], cv = ct[n*32+j];
          float x1 = acc[mi][ni][r], x2 = acc[mi][ni+2][r];
          size_t base = ((size_t)((b*NHEADS+h)*SEQ + n))*HDIM;
          O[base + j]      = f2bf((x1*cv - x2*sv)*qs);
          O[base + j + 32] = f2bf((x1*sv + x2*cv)*qs);
        }
      }
    }
  } else {
    #pragma unroll
    for(int mi=0;mi<4;mi++){
      #pragma unroll
      for(int ni=0;ni<4;ni++){
        int dh = ni*16+lq;
        int m = rbase + mi*16;
        int b = m>>11, n = m&2047;
        s16x4 v;
        #pragma unroll
        for(int r=0;r<4;r++) v[r] = (short)f2bf(acc[mi][ni][r]);
        *(s16x4*)(Vt + ((size_t)((b*NHEADS+h)*HDIM + dh))*SEQ + n) = v;
      }
    }
  }
}

// ---------------- flash attention: 8-wave blocks (512 thr, 256 q), 2-buf LDS, stagger (R16) ----------------
__global__ __launch_bounds__(512) void attn_k(
  const uint16_t* __restrict__ Qr, const uint16_t* __restrict__ Kr, const uint16_t* __restrict__ Vt,
  uint16_t* __restrict__ Ah)
{
  __shared__ char lds[32768];

  int bid = blockIdx.x;
  int w = (bid & 7)*64 + (bid >> 3);    // XCD swizzle: 8 bh per XCD (4MB K/V = one XCD L2)
  int bh = w >> 3, qt = w & 7;
  int tid = threadIdx.x;
  int wid = tid >> 6, lane = tid & 63;
  int l31 = lane & 31, hi = lane >> 5;
  int q0 = qt*256 + wid*32;

  const uint16_t* Qb = Qr + (size_t)bh*SEQ*HDIM;
  const uint16_t* Kb = Kr + (size_t)bh*SEQ*HDIM;
  const uint16_t* Vb = Vt + (size_t)bh*HDIM*SEQ;

  s16x8 qf[4];
  #pragma unroll
  for (int sp=0; sp<4; ++sp)
    qf[sp] = *(const s16x8*)(Qb + (size_t)(q0 + l31)*HDIM + sp*16 + hi*8);

  s16x8 ones;
  #pragma unroll
  for (int j=0;j<8;j++) ones[j] = (short)0x3F80;

  f32x16 zm16;
  #pragma unroll
  for (int r=0;r<16;r++) zm16[r] = -16.0f;

  f32x16 oa[2], lacc;
  #pragma unroll
  for (int r=0;r<16;r++){ oa[0][r]=0.f; oa[1][r]=0.f; lacc[r]=0.f; }

  const int e7 = l31 & 7;
  const int rK = l31*128;
  const int kOff[4]  = { (((0+hi)^e7)<<4), (((2+hi)^e7)<<4), (((4+hi)^e7)<<4), (((6+hi)^e7)<<4) };
  const int vA0 = (((0+hi)^e7)<<4), vA1 = (((2+hi)^e7)<<4);   // sub0
  const int vB0 = (((4+hi)^e7)<<4), vB1 = (((6+hi)^e7)<<4);   // sub1
  const bool odd = (wid & 1) != 0;
  const int kBaseF = odd ? 4096 : 0,   kBaseS = odd ? 0 : 4096;
  const int vF0 = odd ? vB0 : vA0,     vF1 = odd ? vB1 : vA1;
  const int vS0 = odd ? vA0 : vB0,     vS1 = odd ? vA1 : vB1;

  // 512 threads stage one 8KB K-tile + 8KB V-tile: exactly 1 async16 each per thread.
  auto STAGE = [&](int buf, int t){
    const char* Ks = (const char*)(Kb + (size_t)t*64*HDIM);
    char* dK = lds + buf*8192;
    char* dV = lds + 16384 + buf*8192;
    {
      int ci = tid;
      int sc = ci ^ ((ci>>3)&7);        // involution: pre-swizzled source, linear LDS dest
      async16(dK + ci*16, Ks + sc*16);
    }
    {
      int ci = tid;
      int row = ci>>3;
      int sc = (ci&7) ^ (row&7);
      async16(dV + ci*16, (const char*)Vb + ((size_t)row*SEQ + (size_t)t*64)*2 + sc*16);
    }
  };

  auto SUBSTEP = [&](const char* bK, const char* bV, int kbase, int v0, int v1){
    s16x8 kf[4];
    #pragma unroll
    for (int sp=0; sp<4; ++sp)
      kf[sp] = *(const s16x8*)(bK + kbase + rK + kOff[sp]);
    f32x16 sacc = zm16;
    __builtin_amdgcn_s_setprio(1);
    #pragma unroll
    for (int sp=0; sp<4; ++sp)
      sacc = __builtin_amdgcn_mfma_f32_32x32x16_bf16(kf[sp], qf[sp], sacc, 0,0,0);
    __builtin_amdgcn_s_setprio(0);
    s16x8 vf[4];
    #pragma unroll
    for (int db=0; db<2; ++db){
      vf[db*2+0] = *(const s16x8*)(bV + db*4096 + rK + v0);
      vf[db*2+1] = *(const s16x8*)(bV + db*4096 + rK + v1);
    }
    float p[16];
    #pragma unroll
    for (int r=0;r<16;r++) p[r] = fexp2(sacc[r]);
    uint32_t pw[8];
    #pragma unroll
    for (int j=0;j<8;j++)
      asm("v_cvt_pk_bf16_f32 %0, %1, %2" : "=v"(pw[j]) : "v"(p[2*j]), "v"(p[2*j+1]));
    unsigned w0,w1,w2,w3, x0,x1,x2,x3;
    plswap(pw[0], pw[2], w0, w2);
    plswap(pw[1], pw[3], w1, w3);
    plswap(pw[4], pw[6], x0, x2);
    plswap(pw[5], pw[7], x1, x3);
    union { uint32_t wd[4]; s16x8 v; } pa0, pa1;
    pa0.wd[0]=w0; pa0.wd[1]=w1; pa0.wd[2]=w2; pa0.wd[3]=w3;
    pa1.wd[0]=x0; pa1.wd[1]=x1; pa1.wd[2]=x2; pa1.wd[3]=x3;
    __builtin_amdgcn_s_setprio(1);
    oa[0] = __builtin_amdgcn_mfma_f32_32x32x16_bf16(pa0.v, vf[0], oa[0], 0,0,0);
    oa[0] = __builtin_amdgcn_mfma_f32_32x32x16_bf16(pa1.v, vf[1], oa[0], 0,0,0);
    oa[1] = __builtin_amdgcn_mfma_f32_32x32x16_bf16(pa0.v, vf[2], oa[1], 0,0,0);
    oa[1] = __builtin_amdgcn_mfma_f32_32x32x16_bf16(pa1.v, vf[3], oa[1], 0,0,0);
    lacc = __builtin_amdgcn_mfma_f32_32x32x16_bf16(pa0.v, ones, lacc, 0,0,0);
    lacc = __builtin_amdgcn_mfma_f32_32x32x16_bf16(pa1.v, ones, lacc, 0,0,0);
    __builtin_amdgcn_s_setprio(0);
  };

  STAGE(0, 0);
  asm volatile("s_waitcnt vmcnt(0)" ::: "memory");
  __syncthreads();

  const int NT = SEQ/64;
  for (int t=0; t<NT; ++t){
    int cur = t & 1;
    if (t+1 < NT) STAGE(cur^1, t+1);
    const char* bK = lds + cur*8192;
    const char* bV = lds + 16384 + cur*8192;
    SUBSTEP(bK, bV, kBaseF, vF0, vF1);
    SUBSTEP(bK, bV, kBaseS, vS0, vS1);
    asm volatile("s_waitcnt vmcnt(0)" ::: "memory");
    __syncthreads();
  }

  // epilogue: L already in acc layout; normalize and write bf16
  int b = bh >> 4, h = bh & 15;
  #pragma unroll
  for (int r=0;r<16;r++){
    int q = (r&3) + 8*(r>>2) + 4*hi;
    float inv = frcp(lacc[r]);
    size_t mrow = ((size_t)(b*SEQ + q0 + q))*DMODEL + (size_t)h*HDIM + l31;
    #pragma unroll
    for (int db=0; db<2; ++db)
      Ah[mrow + db*32] = f2bf(oa[db][r]*inv);
  }
}

// ---------------- output projection ----------------
__global__ __launch_bounds__(512) void gemm_out_k(
  const uint16_t* __restrict__ Ahp, const uint16_t* __restrict__ WoH, float* __restrict__ C)
{
  __shared__ char lA[256*128], lB[128*128];
  int mx = blockIdx.x;
  int m0 = (((mx & 7) << 2) | (mx >> 3)) * 256;   // XCD-locality swizzle (bijective on [0,32))
  int e0 = blockIdx.y*128;
  f32x4 acc[4][4];
  #pragma unroll
  for(int i=0;i<4;i++){
    #pragma unroll
    for(int j=0;j<4;j++) acc[i][j] = (f32x4){0.f,0.f,0.f,0.f};
  }
  gemm_mainloop64w(Ahp, WoH, m0, e0, lA, lB, acc);
  int t=threadIdx.x, lane=t&63, lq=lane&15, lg=lane>>4;
  int wid=t>>6, wr=wid>>1, wc=wid&1;
  int rbase = m0 + wr*64 + lg*4;
  int cb = e0 + wc*64;
  #pragma unroll
  for(int mi=0;mi<4;mi++){
    #pragma unroll
    for(int ni=0;ni<4;ni++){
      #pragma unroll
      for(int r=0;r<4;r++)
        C[(size_t)(rbase+mi*16+r)*DMODEL + cb + ni*16 + lq] = acc[mi][ni][r];
    }
  }
}

extern "C" void kernel_launch(void* const* d_in, const int* in_sizes, int n_in,
                              void* d_out, int out_size, void* d_ws, size_t ws_size,
                              hipStream_t stream) {
  const float* x  = (const float*)d_in[0];
  const float* Wq = (const float*)d_in[1];
  const float* Wk = (const float*)d_in[2];
  const float* Wv = (const float*)d_in[3];
  const float* Wo = (const float*)d_in[4];
  float* out = (float*)d_out;
  char* ws = (char*)d_ws;

  float* sin_t = (float*)(ws + OFF_SIN);
  float* cos_t = (float*)(ws + OFF_COS);
  uint16_t* xhi = (uint16_t*)(ws + OFF_XHI);
  uint16_t* wqh = (uint16_t*)(ws + OFF_WQH);
  uint16_t* wkh = (uint16_t*)(ws + OFF_WKH);
  uint16_t* wvh = (uint16_t*)(ws + OFF_WVH);
  uint16_t* woh = (uint16_t*)(ws + OFF_WOH);
  uint16_t* Qr  = (uint16_t*)(ws + OFF_QR);
  uint16_t* Kr  = (uint16_t*)(ws + OFF_KR);
  uint16_t* Vt  = (uint16_t*)(ws + OFF_VT);
  uint16_t* ahi = (uint16_t*)(ws + OFF_AHI);

  prep_k<<<dim3(12544),dim3(256),0,stream>>>(x, Wq, Wk, Wv, Wo,
                                             xhi, wqh, wkh, wvh, woh, sin_t, cos_t);

  gemm_qkv_k<<<dim3(MTOT/256, 24),dim3(512),0,stream>>>(xhi, wqh, wkh, wvh,
                                                        sin_t, cos_t, Qr, Kr, Vt);
  attn_k<<<dim3(BATCH*NHEADS*(SEQ/256)),dim3(512),0,stream>>>(Qr, Kr, Vt, ahi);
  gemm_out_k<<<dim3(MTOT/256, 8),dim3(512),0,stream>>>(ahi, woh, out);
}